// Round 1
// 647.477 us; speedup vs baseline: 1.1196x; 1.1196x over previous
//
#include <hip/hip_runtime.h>
#include <cstdint>
#include <cstddef>

#define F_IN 128
#define HC12 256   // HEADS*HID for layers 1/2
#define HC3 484    // OUT_HEADS*N_CLS for layer 3
#define NCLS 121

typedef unsigned short u16;
typedef unsigned int u32;
typedef __attribute__((ext_vector_type(8))) short short8;
typedef __attribute__((ext_vector_type(8))) __fp16 half8;
typedef __attribute__((ext_vector_type(4))) float float4v;

static __device__ __forceinline__ float lrelu(float x) { return x > 0.f ? x : 0.2f * x; }

static __device__ __forceinline__ u16 f2h(float f) {
    union { __fp16 h; u16 u; } v; v.h = (__fp16)f; return v.u;
}
static __device__ __forceinline__ float h2f(u16 u) {
    union { u16 u; __fp16 h; } v; v.u = u; return (float)v.h;
}

static __device__ __forceinline__ void gload16(const u16* g, u16* l) {
    __builtin_amdgcn_global_load_lds((const __attribute__((address_space(1))) void*)g,
                                     (__attribute__((address_space(3))) void*)l,
                                     16, 0, 0);
}

// ---------------- CSR build ----------------
__global__ void hist_kernel(const int* __restrict__ dst, int* __restrict__ deg, int E) {
    int e = blockIdx.x * 256 + threadIdx.x;
    if (e < E) atomicAdd(&deg[dst[e]], 1);
}

__global__ __launch_bounds__(1024) void scan_kernel(const int* __restrict__ deg,
                                                    int* __restrict__ rowp, int N) {
    __shared__ int swave[16];
    __shared__ int s_carry;
    int tid = threadIdx.x;
    int w = tid >> 6, lane = tid & 63;
    if (tid == 0) { rowp[0] = 0; s_carry = 0; }
    __syncthreads();
    for (int base = 0; base < N; base += 4096) {
        int i0 = base + tid * 4;
        int v0 = (i0     < N) ? deg[i0]     : 0;
        int v1 = (i0 + 1 < N) ? deg[i0 + 1] : 0;
        int v2 = (i0 + 2 < N) ? deg[i0 + 2] : 0;
        int v3 = (i0 + 3 < N) ? deg[i0 + 3] : 0;
        int t = v0 + v1 + v2 + v3;
        int sc = t;
#pragma unroll
        for (int off = 1; off < 64; off <<= 1) {
            int u = __shfl_up(sc, off, 64);
            if (lane >= off) sc += u;
        }
        if (lane == 63) swave[w] = sc;
        __syncthreads();
        if (w == 0) {
            int ws = (lane < 16) ? swave[lane] : 0;
#pragma unroll
            for (int off = 1; off < 16; off <<= 1) {
                int u = __shfl_up(ws, off, 64);
                if (lane >= off) ws += u;
            }
            if (lane < 16) swave[lane] = ws;
        }
        __syncthreads();
        int carry = s_carry;
        int tb = carry + ((w > 0) ? swave[w - 1] : 0) + sc - t;
        if (i0     < N) rowp[i0 + 1] = tb + v0;
        if (i0 + 1 < N) rowp[i0 + 2] = tb + v0 + v1;
        if (i0 + 2 < N) rowp[i0 + 3] = tb + v0 + v1 + v2;
        if (i0 + 3 < N) rowp[i0 + 4] = tb + t;
        __syncthreads();
        if (tid == 1023) s_carry = carry + swave[15];
        __syncthreads();
    }
}

__global__ void scatter_kernel(const int* __restrict__ src, const int* __restrict__ dst,
                               const int* __restrict__ rowp, int* __restrict__ cur,
                               int* __restrict__ col, int E) {
    int e = blockIdx.x * 256 + threadIdx.x;
    if (e < E) {
        int d = dst[e];
        int pos = rowp[d] + atomicAdd(&cur[d], 1);
        col[pos] = src[e];
    }
}

// ---------------- fused weight transpose to f16 ----------------
__global__ void cvtT_all_kernel(const float* W1, const float* l1W, const float* W2,
                                const float* W3, const float* l3W,
                                u16* C1, u16* C2, u16* C3) {
    int i = blockIdx.x * 256 + threadIdx.x;
    const float* B; u16* o; int K, N;
    if (i < 32768)       { B = W1;  o = C1;             K = 128; N = 256; }
    else if (i < 65536)  { B = l1W; o = C1 + 256 * 128; K = 128; N = 256; i -= 32768; }
    else if (i < 131072) { B = W2;  o = C2;             K = 256; N = 256; i -= 65536; }
    else if (i < 254976) { B = W3;  o = C3;             K = 256; N = 484; i -= 131072; }
    else if (i < 285952) { B = l3W; o = C3 + 484 * 256; K = 256; N = 121; i -= 254976; }
    else return;
    int n = i % N, k = i / N;
    o[(size_t)n * K + k] = f2h(B[(size_t)k * N + n]);
}

// ---------------- x fp32 -> f16 ----------------
__global__ __launch_bounds__(256) void xcvt_kernel(const float* __restrict__ x,
                                                   u16* __restrict__ o, int total8) {
    int i = blockIdx.x * 256 + threadIdx.x;
    if (i >= total8) return;
    const float4* p = (const float4*)(x + (size_t)i * 8);
    float4 a = p[0], b = p[1];
    union { u16 u[8]; short8 v; } r;
    r.u[0] = f2h(a.x); r.u[1] = f2h(a.y); r.u[2] = f2h(a.z); r.u[3] = f2h(a.w);
    r.u[4] = f2h(b.x); r.u[5] = f2h(b.y); r.u[6] = f2h(b.z); r.u[7] = f2h(b.w);
    *(short8*)(o + (size_t)i * 8) = r.v;
}

// ---------------- f16 MFMA GEMM, 128x128 tile, global_load_lds staging ----------------
#define BM 128
#define BN 128
#define BK 32

__global__ __launch_bounds__(256, 3) void gemm_f16(const u16* __restrict__ A16,
                                                   const u16* __restrict__ BT,
                                                   int M, int K, int Ntot,
                                                   int nx, int ny,
                                                   int Nb, u16* __restrict__ Cb, int strideB,
                                                   float* __restrict__ Cf,
                                                   const float* __restrict__ biasf, int strideF) {
    __shared__ __align__(16) u16 sA[BM * BK];
    __shared__ __align__(16) u16 sB[BN * BK];
    int tid = threadIdx.x;
    int wave = tid >> 6, lane = tid & 63;
    int wr = wave >> 1, wc = wave & 1;

    // XCD-aware block swizzle (unchanged, verified)
    int bid = blockIdx.x;
    int G = nx * 8;
    int g = bid / G;
    int rem = ny - g * 8;
    int rb, cb;
    if (rem >= 8) {
        int r = bid - g * G;
        rb = g * 8 + (r & 7);
        cb = r >> 3;
    } else {
        int t = bid - g * G;
        rb = g * 8 + t % rem;
        cb = t / rem;
    }
    int m0 = rb * BM, n0 = cb * BN;

    int fm = lane & 15;
    int q = lane >> 4;

    // staging: each wave fills rows [wave*32, wave*32+32) of sA and sB.
    // one global_load_lds(16B) covers 16 rows x 64B; lane l -> row l>>2, chunk l&3.
    int srow = lane >> 2;
    int sch = (lane & 3) * 8;
    u16* lA0 = &sA[(wave * 32) * BK];
    u16* lA1 = &sA[(wave * 32 + 16) * BK];
    u16* lB0 = &sB[(wave * 32) * BK];
    u16* lB1 = &sB[(wave * 32 + 16) * BK];
    int ar0 = min(m0 + wave * 32 + srow, M - 1);
    int ar1 = min(m0 + wave * 32 + 16 + srow, M - 1);
    int br0 = min(n0 + wave * 32 + srow, Ntot - 1);
    int br1 = min(n0 + wave * 32 + 16 + srow, Ntot - 1);

    float4v acc[4][4];
#pragma unroll
    for (int i = 0; i < 4; i++)
#pragma unroll
        for (int j = 0; j < 4; j++) acc[i][j] = (float4v){0.f, 0.f, 0.f, 0.f};

    for (int kc = 0; kc < K; kc += BK) {
        gload16(&A16[(size_t)ar0 * K + kc + sch], lA0);
        gload16(&A16[(size_t)ar1 * K + kc + sch], lA1);
        gload16(&BT[(size_t)br0 * K + kc + sch], lB0);
        gload16(&BT[(size_t)br1 * K + kc + sch], lB1);
        __syncthreads();   // drains vmcnt -> LDS tile ready

        half8 ah[4];
#pragma unroll
        for (int mi = 0; mi < 4; mi++)
            ah[mi] = *(const half8*)&sA[(wr * 64 + mi * 16 + fm) * BK + q * 8];
#pragma unroll
        for (int ni = 0; ni < 4; ni++) {
            half8 bh = *(const half8*)&sB[(wc * 64 + ni * 16 + fm) * BK + q * 8];
#pragma unroll
            for (int mi = 0; mi < 4; mi++)
                acc[mi][ni] = __builtin_amdgcn_mfma_f32_16x16x32_f16(ah[mi], bh, acc[mi][ni], 0, 0, 0);
        }
        __syncthreads();   // all reads done before next tile overwrites
    }

#pragma unroll
    for (int mi = 0; mi < 4; mi++) {
#pragma unroll
        for (int ni = 0; ni < 4; ni++) {
            int colg = n0 + wc * 64 + ni * 16 + fm;
            if (colg >= Ntot) continue;
#pragma unroll
            for (int r = 0; r < 4; r++) {
                int rowg = m0 + wr * 64 + mi * 16 + q * 4 + r;
                if (rowg >= M) continue;
                float v = acc[mi][ni][r];
                if (colg < Nb) {
                    Cb[(size_t)rowg * strideB + colg] = f2h(v);
                } else {
                    int cf = colg - Nb;
                    Cf[(size_t)rowg * strideF + cf] = v + biasf[cf];
                }
            }
        }
    }
}

// ---------------- per-node attention coefficients (f16 xh) ----------------
__global__ __launch_bounds__(256) void alpha_kernel(const u16* __restrict__ xh,
                                                    const float* __restrict__ a_s,
                                                    const float* __restrict__ a_d,
                                                    float* __restrict__ as_o,
                                                    float* __restrict__ ad_o, int C) {
    int n = blockIdx.x;
    int w = threadIdx.x >> 6, lane = threadIdx.x & 63;
    const u16* row = xh + (size_t)n * 4 * C + (size_t)w * C;
    float ss = 0.f, sd = 0.f;
    for (int c = lane; c < C; c += 64) {
        float v = h2f(row[c]);
        ss += v * a_s[w * C + c];
        sd += v * a_d[w * C + c];
    }
    for (int o = 32; o; o >>= 1) {
        ss += __shfl_xor(ss, o, 64);
        sd += __shfl_xor(sd, o, 64);
    }
    if (!lane) {
        as_o[n * 4 + w] = ss;
        ad_o[n * 4 + w] = sd;
    }
}

// ---------------- fused softmax stats + per-edge alpha ----------------
__global__ __launch_bounds__(256) void stats_alpha_kernel(const int* __restrict__ rowp,
                                                          const int* __restrict__ col,
                                                          const float* __restrict__ asrc,
                                                          const float* __restrict__ adst,
                                                          float* __restrict__ alphaE, int N) {
    int i = blockIdx.x * 256 + threadIdx.x;
    if (i >= N * 4) return;
    int n = i >> 2, h = i & 3;
    int r0 = rowp[n], r1 = rowp[n + 1];
    float ad = adst[i];
    float m = -3.4e38f, s = 0.f;
    for (int e = r0; e < r1; e++) {
        int sc = col[e];
        float l = lrelu(asrc[sc * 4 + h] + ad);
        float nm = fmaxf(m, l);
        s = s * __expf(m - nm) + __expf(l - nm);
        m = nm;
    }
    float rd = 1.f / (s + 1e-16f);
    for (int e = r0; e < r1; e++) {
        int sc = col[e];
        float l = lrelu(asrc[sc * 4 + h] + ad);
        alphaE[(size_t)e * 4 + h] = __expf(l - m) * rd;
    }
}

// ---------------- gather+FMA aggregate, HC=256 (layers 1/2) ----------------
// outf (fp32, optional) for residual consumers; out16 (f16) feeds next GEMM.
__global__ __launch_bounds__(256) void agg_kernel_256(const u16* __restrict__ xh,
                                                      const int* __restrict__ rowp,
                                                      const int* __restrict__ col,
                                                      const float* __restrict__ alphaE,
                                                      const float* __restrict__ bias,
                                                      const float* __restrict__ res,
                                                      float* __restrict__ outf,
                                                      u16* __restrict__ out16) {
    int n = blockIdx.x, tid = threadIdx.x;
    int r0 = rowp[n], deg = rowp[n + 1] - r0;
    __shared__ int s_src[64];
    __shared__ float s_al[64][4];
    __shared__ float s_part[4][HC12];
    int g = tid >> 6;          // edge group 0..3
    int sub = tid & 63;
    int c = sub * 4;           // channel quad
    int h = sub >> 4;          // c/64
    float a0 = 0.f, a1 = 0.f, a2 = 0.f, a3 = 0.f;
    for (int kb = 0; kb < deg; kb += 64) {
        int cn = min(64, deg - kb);
        __syncthreads();
        if (tid < cn) s_src[tid] = col[r0 + kb + tid];
        for (int idx = tid; idx < cn * 4; idx += 256)
            s_al[idx >> 2][idx & 3] = alphaE[(size_t)(r0 + kb) * 4 + idx];
        __syncthreads();
#pragma unroll 4
        for (int kk = g; kk < cn; kk += 4) {
            uint2 v = *(const uint2*)&xh[(size_t)s_src[kk] * HC12 + c];
            float al = s_al[kk][h];
            a0 += al * h2f((u16)(v.x & 0xffff));
            a1 += al * h2f((u16)(v.x >> 16));
            a2 += al * h2f((u16)(v.y & 0xffff));
            a3 += al * h2f((u16)(v.y >> 16));
        }
    }
    s_part[g][c] = a0; s_part[g][c + 1] = a1; s_part[g][c + 2] = a2; s_part[g][c + 3] = a3;
    __syncthreads();
    float v = s_part[0][tid] + s_part[1][tid] + s_part[2][tid] + s_part[3][tid]
              + bias[tid] + res[(size_t)n * HC12 + tid];
    float act = v > 0.f ? v : expm1f(v);
    if (outf) outf[(size_t)n * HC12 + tid] = act;
    out16[(size_t)n * HC12 + tid] = f2h(act);
}

// ---------------- layer 3 gather: HC=484, mean heads + b3 + lin3 -> d_out ----------------
__global__ __launch_bounds__(256) void agg_out_kernel(const u16* __restrict__ xh,
                                                      const int* __restrict__ rowp,
                                                      const int* __restrict__ col,
                                                      const float* __restrict__ alphaE,
                                                      const float* __restrict__ b3,
                                                      const float* __restrict__ lin3,
                                                      float* __restrict__ out) {
    int n = blockIdx.x, tid = threadIdx.x;
    int r0 = rowp[n], deg = rowp[n + 1] - r0;
    __shared__ int s_src[64];
    __shared__ float s_al[64][4];
    __shared__ float s_out[HC3];
    bool act = tid < 242;
    int c0 = 2 * tid, c1 = c0 + 1;
    int h0 = c0 >= 363 ? 3 : (c0 >= 242 ? 2 : (c0 >= 121 ? 1 : 0));
    int h1 = c1 >= 363 ? 3 : (c1 >= 242 ? 2 : (c1 >= 121 ? 1 : 0));
    float a0 = 0.f, a1 = 0.f;
    for (int kb = 0; kb < deg; kb += 64) {
        int cn = min(64, deg - kb);
        __syncthreads();
        if (tid < cn) s_src[tid] = col[r0 + kb + tid];
        for (int idx = tid; idx < cn * 4; idx += 256)
            s_al[idx >> 2][idx & 3] = alphaE[(size_t)(r0 + kb) * 4 + idx];
        __syncthreads();
        if (act) {
#pragma unroll 4
            for (int kk = 0; kk < cn; kk++) {
                u32 v = *(const u32*)&xh[(size_t)s_src[kk] * HC3 + c0];
                a0 += s_al[kk][h0] * h2f((u16)(v & 0xffff));
                a1 += s_al[kk][h1] * h2f((u16)(v >> 16));
            }
        }
    }
    if (act) { s_out[c0] = a0; s_out[c1] = a1; }
    __syncthreads();
    if (tid < NCLS) {
        float o = 0.25f * (s_out[tid] + s_out[NCLS + tid] + s_out[2 * NCLS + tid] + s_out[3 * NCLS + tid])
                  + b3[tid] + lin3[(size_t)n * NCLS + tid];
        out[(size_t)n * NCLS + tid] = o;
    }
}

extern "C" void kernel_launch(void* const* d_in, const int* in_sizes, int n_in,
                              void* d_out, int out_size, void* d_ws, size_t ws_size,
                              hipStream_t stream) {
    const float* x   = (const float*)d_in[0];
    const int*   ei  = (const int*)d_in[1];
    const float* W1  = (const float*)d_in[2];
    const float* a1s = (const float*)d_in[3];
    const float* a1d = (const float*)d_in[4];
    const float* b1  = (const float*)d_in[5];
    const float* l1W = (const float*)d_in[6];
    const float* l1b = (const float*)d_in[7];
    const float* W2  = (const float*)d_in[8];
    const float* a2s = (const float*)d_in[9];
    const float* a2d = (const float*)d_in[10];
    const float* b2  = (const float*)d_in[11];
    const float* W3  = (const float*)d_in[12];
    const float* a3s = (const float*)d_in[13];
    const float* a3d = (const float*)d_in[14];
    const float* b3  = (const float*)d_in[15];
    const float* l3W = (const float*)d_in[16];
    const float* l3b = (const float*)d_in[17];

    const int N = in_sizes[0] / F_IN;   // 50000
    const int E = in_sizes[1] / 2;      // 400000
    const int* srcv = ei;
    const int* dstv = ei + E;

    char* ws = (char*)d_ws;
    size_t off = 0;
    auto alloc = [&](size_t bytes) -> char* {
        char* p = ws + off;
        off += (bytes + 255) & ~(size_t)255;
        return p;
    };
    u16*   xh   = (u16*)alloc((size_t)N * HC3 * 2);
    u16*   x16  = (u16*)alloc((size_t)N * F_IN * 2);
    u16*   h1f  = (u16*)alloc((size_t)N * HC12 * 2);
    u16*   h2f  = (u16*)alloc((size_t)N * HC12 * 2);
    float* h1   = (float*)alloc((size_t)N * HC12 * 4);
    float* lin  = (float*)alloc((size_t)N * NCLS * 4);
    float* as_  = (float*)alloc((size_t)N * 4 * 4);
    float* ad_  = (float*)alloc((size_t)N * 4 * 4);
    int* rowp   = (int*)alloc((size_t)(N + 1) * 4);
    int* degc   = (int*)alloc((size_t)N * 4);
    int* cur    = (int*)alloc((size_t)N * 4);
    int* col    = (int*)alloc((size_t)E * 4);
    float* alphaE = (float*)alloc((size_t)E * 4 * 4);
    u16* C1 = (u16*)alloc((size_t)512 * 128 * 2);
    u16* C2 = (u16*)alloc((size_t)256 * 256 * 2);
    u16* C3 = (u16*)alloc((size_t)605 * 256 * 2);
    (void)ws_size; (void)n_in; (void)out_size;

    // ---- CSR build ----
    hipMemsetAsync(degc, 0, (size_t)N * 4, stream);
    hipMemsetAsync(cur, 0, (size_t)N * 4, stream);
    hist_kernel<<<(E + 255) / 256, 256, 0, stream>>>(dstv, degc, E);
    scan_kernel<<<1, 1024, 0, stream>>>(degc, rowp, N);
    scatter_kernel<<<(E + 255) / 256, 256, 0, stream>>>(srcv, dstv, rowp, cur, col, E);

    // ---- weight transpose + x conversion ----
    cvtT_all_kernel<<<(285952 + 255) / 256, 256, 0, stream>>>(W1, l1W, W2, W3, l3W, C1, C2, C3);
    xcvt_kernel<<<(N * F_IN / 8 + 255) / 256, 256, 0, stream>>>(x, x16, N * F_IN / 8);

    int ny = (N + BM - 1) / BM;
    int sgrid = (N * 4 + 255) / 256;

    // ---- layer 1: one GEMM, N=512 (cols 0-255 -> xh f16, 256-511 -> h1 fp32 + l1b) ----
    gemm_f16<<<4 * ny, 256, 0, stream>>>(x16, C1, N, F_IN, 512, 4, ny,
                                         256, xh, 256, h1, l1b, 256);
    alpha_kernel<<<N, 256, 0, stream>>>(xh, a1s, a1d, as_, ad_, 64);
    stats_alpha_kernel<<<sgrid, 256, 0, stream>>>(rowp, col, as_, ad_, alphaE, N);
    agg_kernel_256<<<N, 256, 0, stream>>>(xh, rowp, col, alphaE, b1, h1, h1, h1f);

    // ---- layer 2: N=256, f16-only output ----
    gemm_f16<<<2 * ny, 256, 0, stream>>>(h1f, C2, N, HC12, 256, 2, ny,
                                         256, xh, 256, nullptr, nullptr, 0);
    alpha_kernel<<<N, 256, 0, stream>>>(xh, a2s, a2d, as_, ad_, 64);
    stats_alpha_kernel<<<sgrid, 256, 0, stream>>>(rowp, col, as_, ad_, alphaE, N);
    agg_kernel_256<<<N, 256, 0, stream>>>(xh, rowp, col, alphaE, b2, h1, nullptr, h2f);

    // ---- layer 3: one GEMM, N=605 (cols 0-483 -> xh f16, 484-604 -> lin fp32 + l3b) ----
    gemm_f16<<<5 * ny, 256, 0, stream>>>(h2f, C3, N, HC12, 605, 5, ny,
                                         484, xh, 484, lin, l3b, NCLS);
    alpha_kernel<<<N, 256, 0, stream>>>(xh, a3s, a3d, as_, ad_, NCLS);
    stats_alpha_kernel<<<sgrid, 256, 0, stream>>>(rowp, col, as_, ad_, alphaE, N);
    agg_out_kernel<<<N, 256, 0, stream>>>(xh, rowp, col, alphaE, b3, lin, (float*)d_out);
}

// Round 2
// 543.881 us; speedup vs baseline: 1.3329x; 1.1905x over previous
//
#include <hip/hip_runtime.h>
#include <cstdint>
#include <cstddef>

#define F_IN 128
#define HC12 256   // HEADS*HID for layers 1/2
#define HC3 484    // OUT_HEADS*N_CLS for layer 3
#define NCLS 121

typedef unsigned short u16;
typedef unsigned int u32;
typedef __attribute__((ext_vector_type(8))) short short8;
typedef __attribute__((ext_vector_type(8))) __fp16 half8;
typedef __attribute__((ext_vector_type(4))) float float4v;

static __device__ __forceinline__ float lrelu(float x) { return x > 0.f ? x : 0.2f * x; }

static __device__ __forceinline__ u16 f2h(float f) {
    union { __fp16 h; u16 u; } v; v.h = (__fp16)f; return v.u;
}
static __device__ __forceinline__ float h2f(u16 u) {
    union { u16 u; __fp16 h; } v; v.u = u; return (float)v.h;
}

static __device__ __forceinline__ void gload16(const u16* g, u16* l) {
    __builtin_amdgcn_global_load_lds((const __attribute__((address_space(1))) void*)g,
                                     (__attribute__((address_space(3))) void*)l,
                                     16, 0, 0);
}

// ---------------- CSR build ----------------
__global__ void hist_kernel(const int* __restrict__ dst, int* __restrict__ deg, int E) {
    int e = blockIdx.x * 256 + threadIdx.x;
    if (e < E) atomicAdd(&deg[dst[e]], 1);
}

__global__ __launch_bounds__(1024) void scan_kernel(const int* __restrict__ deg,
                                                    int* __restrict__ rowp, int N) {
    __shared__ int swave[16];
    __shared__ int s_carry;
    int tid = threadIdx.x;
    int w = tid >> 6, lane = tid & 63;
    if (tid == 0) { rowp[0] = 0; s_carry = 0; }
    __syncthreads();
    for (int base = 0; base < N; base += 4096) {
        int i0 = base + tid * 4;
        int v0 = (i0     < N) ? deg[i0]     : 0;
        int v1 = (i0 + 1 < N) ? deg[i0 + 1] : 0;
        int v2 = (i0 + 2 < N) ? deg[i0 + 2] : 0;
        int v3 = (i0 + 3 < N) ? deg[i0 + 3] : 0;
        int t = v0 + v1 + v2 + v3;
        int sc = t;
#pragma unroll
        for (int off = 1; off < 64; off <<= 1) {
            int u = __shfl_up(sc, off, 64);
            if (lane >= off) sc += u;
        }
        if (lane == 63) swave[w] = sc;
        __syncthreads();
        if (w == 0) {
            int ws = (lane < 16) ? swave[lane] : 0;
#pragma unroll
            for (int off = 1; off < 16; off <<= 1) {
                int u = __shfl_up(ws, off, 64);
                if (lane >= off) ws += u;
            }
            if (lane < 16) swave[lane] = ws;
        }
        __syncthreads();
        int carry = s_carry;
        int tb = carry + ((w > 0) ? swave[w - 1] : 0) + sc - t;
        if (i0     < N) rowp[i0 + 1] = tb + v0;
        if (i0 + 1 < N) rowp[i0 + 2] = tb + v0 + v1;
        if (i0 + 2 < N) rowp[i0 + 3] = tb + v0 + v1 + v2;
        if (i0 + 3 < N) rowp[i0 + 4] = tb + t;
        __syncthreads();
        if (tid == 1023) s_carry = carry + swave[15];
        __syncthreads();
    }
}

__global__ void scatter_kernel(const int* __restrict__ src, const int* __restrict__ dst,
                               const int* __restrict__ rowp, int* __restrict__ cur,
                               int* __restrict__ col, int E) {
    int e = blockIdx.x * 256 + threadIdx.x;
    if (e < E) {
        int d = dst[e];
        int pos = rowp[d] + atomicAdd(&cur[d], 1);
        col[pos] = src[e];
    }
}

// ---------------- fused weight transpose to f16 ----------------
__global__ void cvtT_all_kernel(const float* W1, const float* l1W, const float* W2,
                                const float* W3, const float* l3W,
                                u16* C1, u16* C2, u16* C3) {
    int i = blockIdx.x * 256 + threadIdx.x;
    const float* B; u16* o; int K, N;
    if (i < 32768)       { B = W1;  o = C1;             K = 128; N = 256; }
    else if (i < 65536)  { B = l1W; o = C1 + 256 * 128; K = 128; N = 256; i -= 32768; }
    else if (i < 131072) { B = W2;  o = C2;             K = 256; N = 256; i -= 65536; }
    else if (i < 254976) { B = W3;  o = C3;             K = 256; N = 484; i -= 131072; }
    else if (i < 285952) { B = l3W; o = C3 + 484 * 256; K = 256; N = 121; i -= 254976; }
    else return;
    int n = i % N, k = i / N;
    o[(size_t)n * K + k] = f2h(B[(size_t)k * N + n]);
}

// ---------------- x fp32 -> f16 ----------------
__global__ __launch_bounds__(256) void xcvt_kernel(const float* __restrict__ x,
                                                   u16* __restrict__ o, int total8) {
    int i = blockIdx.x * 256 + threadIdx.x;
    if (i >= total8) return;
    const float4* p = (const float4*)(x + (size_t)i * 8);
    float4 a = p[0], b = p[1];
    union { u16 u[8]; short8 v; } r;
    r.u[0] = f2h(a.x); r.u[1] = f2h(a.y); r.u[2] = f2h(a.z); r.u[3] = f2h(a.w);
    r.u[4] = f2h(b.x); r.u[5] = f2h(b.y); r.u[6] = f2h(b.z); r.u[7] = f2h(b.w);
    *(short8*)(o + (size_t)i * 8) = r.v;
}

// ---------------- f16 MFMA GEMM, 128x128 tile, global_load_lds staging ----------------
#define BM 128
#define BN 128
#define BK 32

__global__ __launch_bounds__(256, 3) void gemm_f16(const u16* __restrict__ A16,
                                                   const u16* __restrict__ BT,
                                                   int M, int K, int Ntot,
                                                   int nx, int ny,
                                                   int Nb, u16* __restrict__ Cb, int strideB,
                                                   float* __restrict__ Cf,
                                                   const float* __restrict__ biasf, int strideF) {
    __shared__ __align__(16) u16 sA[BM * BK];
    __shared__ __align__(16) u16 sB[BN * BK];
    int tid = threadIdx.x;
    int wave = tid >> 6, lane = tid & 63;
    int wr = wave >> 1, wc = wave & 1;

    // XCD-aware block swizzle
    int bid = blockIdx.x;
    int G = nx * 8;
    int g = bid / G;
    int rem = ny - g * 8;
    int rb, cb;
    if (rem >= 8) {
        int r = bid - g * G;
        rb = g * 8 + (r & 7);
        cb = r >> 3;
    } else {
        int t = bid - g * G;
        rb = g * 8 + t % rem;
        cb = t / rem;
    }
    int m0 = rb * BM, n0 = cb * BN;

    int fm = lane & 15;
    int q = lane >> 4;

    int srow = lane >> 2;
    int sch = (lane & 3) * 8;
    u16* lA0 = &sA[(wave * 32) * BK];
    u16* lA1 = &sA[(wave * 32 + 16) * BK];
    u16* lB0 = &sB[(wave * 32) * BK];
    u16* lB1 = &sB[(wave * 32 + 16) * BK];
    int ar0 = min(m0 + wave * 32 + srow, M - 1);
    int ar1 = min(m0 + wave * 32 + 16 + srow, M - 1);
    int br0 = min(n0 + wave * 32 + srow, Ntot - 1);
    int br1 = min(n0 + wave * 32 + 16 + srow, Ntot - 1);

    float4v acc[4][4];
#pragma unroll
    for (int i = 0; i < 4; i++)
#pragma unroll
        for (int j = 0; j < 4; j++) acc[i][j] = (float4v){0.f, 0.f, 0.f, 0.f};

    for (int kc = 0; kc < K; kc += BK) {
        gload16(&A16[(size_t)ar0 * K + kc + sch], lA0);
        gload16(&A16[(size_t)ar1 * K + kc + sch], lA1);
        gload16(&BT[(size_t)br0 * K + kc + sch], lB0);
        gload16(&BT[(size_t)br1 * K + kc + sch], lB1);
        __syncthreads();

        half8 ah[4];
#pragma unroll
        for (int mi = 0; mi < 4; mi++)
            ah[mi] = *(const half8*)&sA[(wr * 64 + mi * 16 + fm) * BK + q * 8];
#pragma unroll
        for (int ni = 0; ni < 4; ni++) {
            half8 bh = *(const half8*)&sB[(wc * 64 + ni * 16 + fm) * BK + q * 8];
#pragma unroll
            for (int mi = 0; mi < 4; mi++)
                acc[mi][ni] = __builtin_amdgcn_mfma_f32_16x16x32_f16(ah[mi], bh, acc[mi][ni], 0, 0, 0);
        }
        __syncthreads();
    }

#pragma unroll
    for (int mi = 0; mi < 4; mi++) {
#pragma unroll
        for (int ni = 0; ni < 4; ni++) {
            int colg = n0 + wc * 64 + ni * 16 + fm;
            if (colg >= Ntot) continue;
#pragma unroll
            for (int r = 0; r < 4; r++) {
                int rowg = m0 + wr * 64 + mi * 16 + q * 4 + r;
                if (rowg >= M) continue;
                float v = acc[mi][ni][r];
                if (colg < Nb) {
                    Cb[(size_t)rowg * strideB + colg] = f2h(v);
                } else {
                    int cf = colg - Nb;
                    Cf[(size_t)rowg * strideF + cf] = v + biasf[cf];
                }
            }
        }
    }
}

// ---------------- wave-per-node attention coefficients, C=64 (layers 1/2) ----------------
// lane owns 4 channels (uint2); head = lane>>4; reduce within 16-lane head groups.
__global__ __launch_bounds__(256) void alpha_wave_256(const u16* __restrict__ xh,
                                                      const float* __restrict__ a_s,
                                                      const float* __restrict__ a_d,
                                                      float* __restrict__ as_o,
                                                      float* __restrict__ ad_o, int N) {
    int lane = threadIdx.x & 63;
    int n = blockIdx.x * 4 + (threadIdx.x >> 6);
    if (n >= N) return;
    int c = lane * 4;
    uint2 v = *(const uint2*)&xh[(size_t)n * HC12 + c];
    float4 s4 = *(const float4*)&a_s[c];
    float4 d4 = *(const float4*)&a_d[c];
    float x0 = h2f((u16)(v.x & 0xffff)), x1 = h2f((u16)(v.x >> 16));
    float x2 = h2f((u16)(v.y & 0xffff)), x3 = h2f((u16)(v.y >> 16));
    float ss = x0 * s4.x + x1 * s4.y + x2 * s4.z + x3 * s4.w;
    float sd = x0 * d4.x + x1 * d4.y + x2 * d4.z + x3 * d4.w;
#pragma unroll
    for (int o = 1; o < 16; o <<= 1) {
        ss += __shfl_xor(ss, o, 64);
        sd += __shfl_xor(sd, o, 64);
    }
    if ((lane & 15) == 0) {
        as_o[n * 4 + (lane >> 4)] = ss;
        ad_o[n * 4 + (lane >> 4)] = sd;
    }
}

// ---------------- per-node attention coefficients (layer 3, C=121) ----------------
__global__ __launch_bounds__(256) void alpha_kernel(const u16* __restrict__ xh,
                                                    const float* __restrict__ a_s,
                                                    const float* __restrict__ a_d,
                                                    float* __restrict__ as_o,
                                                    float* __restrict__ ad_o, int C) {
    int n = blockIdx.x;
    int w = threadIdx.x >> 6, lane = threadIdx.x & 63;
    const u16* row = xh + (size_t)n * 4 * C + (size_t)w * C;
    float ss = 0.f, sd = 0.f;
    for (int c = lane; c < C; c += 64) {
        float v = h2f(row[c]);
        ss += v * a_s[w * C + c];
        sd += v * a_d[w * C + c];
    }
    for (int o = 32; o; o >>= 1) {
        ss += __shfl_xor(ss, o, 64);
        sd += __shfl_xor(sd, o, 64);
    }
    if (!lane) {
        as_o[n * 4 + w] = ss;
        ad_o[n * 4 + w] = sd;
    }
}

// ---------------- fused softmax stats + per-edge alpha ----------------
__global__ __launch_bounds__(256) void stats_alpha_kernel(const int* __restrict__ rowp,
                                                          const int* __restrict__ col,
                                                          const float* __restrict__ asrc,
                                                          const float* __restrict__ adst,
                                                          float* __restrict__ alphaE, int N) {
    int i = blockIdx.x * 256 + threadIdx.x;
    if (i >= N * 4) return;
    int n = i >> 2, h = i & 3;
    int r0 = rowp[n], r1 = rowp[n + 1];
    float ad = adst[i];
    float m = -3.4e38f, s = 0.f;
    for (int e = r0; e < r1; e++) {
        int sc = col[e];
        float l = lrelu(asrc[sc * 4 + h] + ad);
        float nm = fmaxf(m, l);
        s = s * __expf(m - nm) + __expf(l - nm);
        m = nm;
    }
    float rd = 1.f / (s + 1e-16f);
    for (int e = r0; e < r1; e++) {
        int sc = col[e];
        float l = lrelu(asrc[sc * 4 + h] + ad);
        alphaE[(size_t)e * 4 + h] = __expf(l - m) * rd;
    }
}

// ---------------- wave-per-node aggregate, HC=256 (layers 1/2) ----------------
// lane owns 4 channels; src index + all-head alphas broadcast via shfl.
// Per 16-edge chunk: col[kb+lane&15] (indices) and alphaE[kb*4+lane] (4 heads x 16 edges).
__global__ __launch_bounds__(256) void agg_wave_256(const u16* __restrict__ xh,
                                                    const int* __restrict__ rowp,
                                                    const int* __restrict__ col,
                                                    const float* __restrict__ alphaE,
                                                    const float* __restrict__ bias,
                                                    const float* __restrict__ res,
                                                    float* __restrict__ outf,
                                                    u16* __restrict__ out16, int N) {
    int lane = threadIdx.x & 63;
    int n = blockIdx.x * 4 + (threadIdx.x >> 6);
    if (n >= N) return;
    int r0 = rowp[n], r1 = rowp[n + 1];
    int c = lane * 4;
    int h = lane >> 4;
    float a0 = 0.f, a1 = 0.f, a2 = 0.f, a3 = 0.f;
    for (int kb = r0; kb < r1; kb += 16) {
        int cn = min(16, r1 - kb);
        int cidx = col[kb + (lane & 15)];
        float alv = alphaE[(size_t)kb * 4 + lane];
        for (int k = 0; k < cn; k++) {
            int src = __shfl(cidx, k, 64);
            float al = __shfl(alv, k * 4 + h, 64);
            uint2 v = *(const uint2*)&xh[(size_t)src * HC12 + c];
            a0 += al * h2f((u16)(v.x & 0xffff));
            a1 += al * h2f((u16)(v.x >> 16));
            a2 += al * h2f((u16)(v.y & 0xffff));
            a3 += al * h2f((u16)(v.y >> 16));
        }
    }
    float4 bv = *(const float4*)&bias[c];
    float4 rv = *(const float4*)&res[(size_t)n * HC12 + c];
    float v0 = a0 + bv.x + rv.x;
    float v1 = a1 + bv.y + rv.y;
    float v2 = a2 + bv.z + rv.z;
    float v3 = a3 + bv.w + rv.w;
    float e0 = v0 > 0.f ? v0 : expm1f(v0);
    float e1 = v1 > 0.f ? v1 : expm1f(v1);
    float e2 = v2 > 0.f ? v2 : expm1f(v2);
    float e3 = v3 > 0.f ? v3 : expm1f(v3);
    if (outf) {
        float4 o4; o4.x = e0; o4.y = e1; o4.z = e2; o4.w = e3;
        *(float4*)&outf[(size_t)n * HC12 + c] = o4;
    }
    union { u16 u[4]; uint2 v; } p;
    p.u[0] = f2h(e0); p.u[1] = f2h(e1); p.u[2] = f2h(e2); p.u[3] = f2h(e3);
    *(uint2*)&out16[(size_t)n * HC12 + c] = p.v;
}

// ---------------- wave-per-node layer-3 aggregate: HC=484, mean heads + b3 + lin3 ----------------
// lane owns 8 channels (uint4), lanes 0..60 active; head-mean via small per-wave LDS.
__global__ __launch_bounds__(256) void agg_wave_out(const u16* __restrict__ xh,
                                                    const int* __restrict__ rowp,
                                                    const int* __restrict__ col,
                                                    const float* __restrict__ alphaE,
                                                    const float* __restrict__ b3,
                                                    const float* __restrict__ lin3,
                                                    float* __restrict__ out, int N) {
    __shared__ float s_acc[4][488];
    int w = threadIdx.x >> 6, lane = threadIdx.x & 63;
    int n = blockIdx.x * 4 + w;
    int r0 = 0, r1 = 0;
    if (n < N) { r0 = rowp[n]; r1 = rowp[n + 1]; }
    int c = lane * 8;
    int hA = c / 121; if (hA > 3) hA = 3;
    int hB = (c + 7) / 121; if (hB > 3) hB = 3;
    int split = 121 * (hA + 1) - c;   // j < split -> head hA, else hB
    float acc[8] = {0.f, 0.f, 0.f, 0.f, 0.f, 0.f, 0.f, 0.f};
    for (int kb = r0; kb < r1; kb += 16) {
        int cn = min(16, r1 - kb);
        int cidx = col[kb + (lane & 15)];
        float alv = alphaE[(size_t)kb * 4 + lane];
        for (int k = 0; k < cn; k++) {
            int src = __shfl(cidx, k, 64);
            float alA = __shfl(alv, k * 4 + hA, 64);
            float alB = __shfl(alv, k * 4 + hB, 64);
            if (lane < 61) {
                uint4 v = *(const uint4*)&xh[(size_t)src * HC3 + c];
                u32 ww[4] = {v.x, v.y, v.z, v.w};
#pragma unroll
                for (int jj = 0; jj < 4; jj++) {
                    float lo = h2f((u16)(ww[jj] & 0xffff));
                    float hi = h2f((u16)(ww[jj] >> 16));
                    float aLo = (2 * jj     < split) ? alA : alB;
                    float aHi = (2 * jj + 1 < split) ? alA : alB;
                    acc[2 * jj]     += aLo * lo;
                    acc[2 * jj + 1] += aHi * hi;
                }
            }
        }
    }
    if (n < N && lane < 61) {
#pragma unroll
        for (int j = 0; j < 8; j++)
            if (c + j < HC3) s_acc[w][c + j] = acc[j];
    }
    __syncthreads();
    if (n < N) {
        for (int j = lane; j < NCLS; j += 64) {
            float o = 0.25f * (s_acc[w][j] + s_acc[w][j + 121] + s_acc[w][j + 242] + s_acc[w][j + 363])
                      + b3[j] + lin3[(size_t)n * NCLS + j];
            out[(size_t)n * NCLS + j] = o;
        }
    }
}

extern "C" void kernel_launch(void* const* d_in, const int* in_sizes, int n_in,
                              void* d_out, int out_size, void* d_ws, size_t ws_size,
                              hipStream_t stream) {
    const float* x   = (const float*)d_in[0];
    const int*   ei  = (const int*)d_in[1];
    const float* W1  = (const float*)d_in[2];
    const float* a1s = (const float*)d_in[3];
    const float* a1d = (const float*)d_in[4];
    const float* b1  = (const float*)d_in[5];
    const float* l1W = (const float*)d_in[6];
    const float* l1b = (const float*)d_in[7];
    const float* W2  = (const float*)d_in[8];
    const float* a2s = (const float*)d_in[9];
    const float* a2d = (const float*)d_in[10];
    const float* b2  = (const float*)d_in[11];
    const float* W3  = (const float*)d_in[12];
    const float* a3s = (const float*)d_in[13];
    const float* a3d = (const float*)d_in[14];
    const float* b3  = (const float*)d_in[15];
    const float* l3W = (const float*)d_in[16];
    const float* l3b = (const float*)d_in[17];

    const int N = in_sizes[0] / F_IN;   // 50000
    const int E = in_sizes[1] / 2;      // 400000
    const int* srcv = ei;
    const int* dstv = ei + E;

    char* ws = (char*)d_ws;
    size_t off = 0;
    auto alloc = [&](size_t bytes) -> char* {
        char* p = ws + off;
        off += (bytes + 255) & ~(size_t)255;
        return p;
    };
    u16*   xh   = (u16*)alloc((size_t)N * HC3 * 2 + 256);
    u16*   x16  = (u16*)alloc((size_t)N * F_IN * 2);
    u16*   h1f  = (u16*)alloc((size_t)N * HC12 * 2);
    u16*   h2f  = (u16*)alloc((size_t)N * HC12 * 2);
    float* h1   = (float*)alloc((size_t)N * HC12 * 4);
    float* lin  = (float*)alloc((size_t)N * NCLS * 4);
    float* as_  = (float*)alloc((size_t)N * 4 * 4);
    float* ad_  = (float*)alloc((size_t)N * 4 * 4);
    int* rowp   = (int*)alloc((size_t)(N + 1) * 4);
    int* degc   = (int*)alloc((size_t)N * 4);
    int* cur    = (int*)alloc((size_t)N * 4);
    int* col    = (int*)alloc((size_t)E * 4 + 256);       // pad: chunked wave reads
    float* alphaE = (float*)alloc((size_t)E * 4 * 4 + 256); // pad: chunked wave reads
    u16* C1 = (u16*)alloc((size_t)512 * 128 * 2);
    u16* C2 = (u16*)alloc((size_t)256 * 256 * 2);
    u16* C3 = (u16*)alloc((size_t)605 * 256 * 2);
    (void)ws_size; (void)n_in; (void)out_size;

    // ---- CSR build ----
    hipMemsetAsync(degc, 0, (size_t)N * 4, stream);
    hipMemsetAsync(cur, 0, (size_t)N * 4, stream);
    hist_kernel<<<(E + 255) / 256, 256, 0, stream>>>(dstv, degc, E);
    scan_kernel<<<1, 1024, 0, stream>>>(degc, rowp, N);
    scatter_kernel<<<(E + 255) / 256, 256, 0, stream>>>(srcv, dstv, rowp, cur, col, E);

    // ---- weight transpose + x conversion ----
    cvtT_all_kernel<<<(285952 + 255) / 256, 256, 0, stream>>>(W1, l1W, W2, W3, l3W, C1, C2, C3);
    xcvt_kernel<<<(N * F_IN / 8 + 255) / 256, 256, 0, stream>>>(x, x16, N * F_IN / 8);

    int ny = (N + BM - 1) / BM;
    int sgrid = (N * 4 + 255) / 256;
    int wgrid = (N + 3) / 4;

    // ---- layer 1: one GEMM, N=512 (cols 0-255 -> xh f16, 256-511 -> h1 fp32 + l1b) ----
    gemm_f16<<<4 * ny, 256, 0, stream>>>(x16, C1, N, F_IN, 512, 4, ny,
                                         256, xh, 256, h1, l1b, 256);
    alpha_wave_256<<<wgrid, 256, 0, stream>>>(xh, a1s, a1d, as_, ad_, N);
    stats_alpha_kernel<<<sgrid, 256, 0, stream>>>(rowp, col, as_, ad_, alphaE, N);
    agg_wave_256<<<wgrid, 256, 0, stream>>>(xh, rowp, col, alphaE, b1, h1, h1, h1f, N);

    // ---- layer 2: N=256, f16-only output ----
    gemm_f16<<<2 * ny, 256, 0, stream>>>(h1f, C2, N, HC12, 256, 2, ny,
                                         256, xh, 256, nullptr, nullptr, 0);
    alpha_wave_256<<<wgrid, 256, 0, stream>>>(xh, a2s, a2d, as_, ad_, N);
    stats_alpha_kernel<<<sgrid, 256, 0, stream>>>(rowp, col, as_, ad_, alphaE, N);
    agg_wave_256<<<wgrid, 256, 0, stream>>>(xh, rowp, col, alphaE, b2, h1, nullptr, h2f, N);

    // ---- layer 3: one GEMM, N=605 (cols 0-483 -> xh f16, 484-604 -> lin fp32 + l3b) ----
    gemm_f16<<<5 * ny, 256, 0, stream>>>(h2f, C3, N, HC12, 605, 5, ny,
                                         484, xh, 484, lin, l3b, NCLS);
    alpha_kernel<<<N, 256, 0, stream>>>(xh, a3s, a3d, as_, ad_, NCLS);
    stats_alpha_kernel<<<sgrid, 256, 0, stream>>>(rowp, col, as_, ad_, alphaE, N);
    agg_wave_out<<<wgrid, 256, 0, stream>>>(xh, rowp, col, alphaE, b3, lin, (float*)d_out, N);
}

// Round 3
// 539.241 us; speedup vs baseline: 1.3443x; 1.0086x over previous
//
#include <hip/hip_runtime.h>
#include <cstdint>
#include <cstddef>

#define F_IN 128
#define HC12 256   // HEADS*HID for layers 1/2
#define HC3 484    // OUT_HEADS*N_CLS for layer 3
#define HC3P 488   // padded row stride for layer-3 activations (4 heads x 122)
#define NCLS 121

typedef unsigned short u16;
typedef unsigned int u32;
typedef __attribute__((ext_vector_type(8))) short short8;
typedef __attribute__((ext_vector_type(8))) __fp16 half8;
typedef __attribute__((ext_vector_type(4))) float float4v;

static __device__ __forceinline__ float lrelu(float x) { return x > 0.f ? x : 0.2f * x; }

static __device__ __forceinline__ u16 f2h(float f) {
    union { __fp16 h; u16 u; } v; v.h = (__fp16)f; return v.u;
}
static __device__ __forceinline__ float h2f(u16 u) {
    union { u16 u; __fp16 h; } v; v.u = u; return (float)v.h;
}

static __device__ __forceinline__ void gload16(const u16* g, u16* l) {
    __builtin_amdgcn_global_load_lds((const __attribute__((address_space(1))) void*)g,
                                     (__attribute__((address_space(3))) void*)l,
                                     16, 0, 0);
}

// ---------------- CSR build ----------------
__global__ void hist_kernel(const int* __restrict__ dst, int* __restrict__ deg, int E) {
    int e = blockIdx.x * 256 + threadIdx.x;
    if (e < E) atomicAdd(&deg[dst[e]], 1);
}

__global__ __launch_bounds__(1024) void scan_kernel(const int* __restrict__ deg,
                                                    int* __restrict__ rowp, int N) {
    __shared__ int swave[16];
    __shared__ int s_carry;
    int tid = threadIdx.x;
    int w = tid >> 6, lane = tid & 63;
    if (tid == 0) { rowp[0] = 0; s_carry = 0; }
    __syncthreads();
    for (int base = 0; base < N; base += 4096) {
        int i0 = base + tid * 4;
        int v0 = (i0     < N) ? deg[i0]     : 0;
        int v1 = (i0 + 1 < N) ? deg[i0 + 1] : 0;
        int v2 = (i0 + 2 < N) ? deg[i0 + 2] : 0;
        int v3 = (i0 + 3 < N) ? deg[i0 + 3] : 0;
        int t = v0 + v1 + v2 + v3;
        int sc = t;
#pragma unroll
        for (int off = 1; off < 64; off <<= 1) {
            int u = __shfl_up(sc, off, 64);
            if (lane >= off) sc += u;
        }
        if (lane == 63) swave[w] = sc;
        __syncthreads();
        if (w == 0) {
            int ws = (lane < 16) ? swave[lane] : 0;
#pragma unroll
            for (int off = 1; off < 16; off <<= 1) {
                int u = __shfl_up(ws, off, 64);
                if (lane >= off) ws += u;
            }
            if (lane < 16) swave[lane] = ws;
        }
        __syncthreads();
        int carry = s_carry;
        int tb = carry + ((w > 0) ? swave[w - 1] : 0) + sc - t;
        if (i0     < N) rowp[i0 + 1] = tb + v0;
        if (i0 + 1 < N) rowp[i0 + 2] = tb + v0 + v1;
        if (i0 + 2 < N) rowp[i0 + 3] = tb + v0 + v1 + v2;
        if (i0 + 3 < N) rowp[i0 + 4] = tb + t;
        __syncthreads();
        if (tid == 1023) s_carry = carry + swave[15];
        __syncthreads();
    }
}

__global__ void scatter_kernel(const int* __restrict__ src, const int* __restrict__ dst,
                               const int* __restrict__ rowp, int* __restrict__ cur,
                               int* __restrict__ col, int E) {
    int e = blockIdx.x * 256 + threadIdx.x;
    if (e < E) {
        int d = dst[e];
        int pos = rowp[d] + atomicAdd(&cur[d], 1);
        col[pos] = src[e];
    }
}

// ---------------- fused weight transpose to f16 ----------------
__global__ void cvtT_all_kernel(const float* W1, const float* l1W, const float* W2,
                                const float* W3, const float* l3W,
                                u16* C1, u16* C2, u16* C3) {
    int i = blockIdx.x * 256 + threadIdx.x;
    const float* B; u16* o; int K, N;
    if (i < 32768)       { B = W1;  o = C1;             K = 128; N = 256; }
    else if (i < 65536)  { B = l1W; o = C1 + 256 * 128; K = 128; N = 256; i -= 32768; }
    else if (i < 131072) { B = W2;  o = C2;             K = 256; N = 256; i -= 65536; }
    else if (i < 254976) { B = W3;  o = C3;             K = 256; N = 484; i -= 131072; }
    else if (i < 285952) { B = l3W; o = C3 + 484 * 256; K = 256; N = 121; i -= 254976; }
    else return;
    int n = i % N, k = i / N;
    o[(size_t)n * K + k] = f2h(B[(size_t)k * N + n]);
}

// ---------------- x fp32 -> f16 ----------------
__global__ __launch_bounds__(256) void xcvt_kernel(const float* __restrict__ x,
                                                   u16* __restrict__ o, int total8) {
    int i = blockIdx.x * 256 + threadIdx.x;
    if (i >= total8) return;
    const float4* p = (const float4*)(x + (size_t)i * 8);
    float4 a = p[0], b = p[1];
    union { u16 u[8]; short8 v; } r;
    r.u[0] = f2h(a.x); r.u[1] = f2h(a.y); r.u[2] = f2h(a.z); r.u[3] = f2h(a.w);
    r.u[4] = f2h(b.x); r.u[5] = f2h(b.y); r.u[6] = f2h(b.z); r.u[7] = f2h(b.w);
    *(short8*)(o + (size_t)i * 8) = r.v;
}

// ---------------- f16 MFMA GEMM, 128x128 tile, global_load_lds staging ----------------
#define BM 128
#define BN 128
#define BK 32

__global__ __launch_bounds__(256, 3) void gemm_f16(const u16* __restrict__ A16,
                                                   const u16* __restrict__ BT,
                                                   int M, int K, int Ntot,
                                                   int nx, int ny,
                                                   int Nb, u16* __restrict__ Cb, int strideB,
                                                   int pad121,
                                                   float* __restrict__ Cf,
                                                   const float* __restrict__ biasf, int strideF) {
    __shared__ __align__(16) u16 sA[BM * BK];
    __shared__ __align__(16) u16 sB[BN * BK];
    int tid = threadIdx.x;
    int wave = tid >> 6, lane = tid & 63;
    int wr = wave >> 1, wc = wave & 1;

    // XCD-aware block swizzle
    int bid = blockIdx.x;
    int G = nx * 8;
    int g = bid / G;
    int rem = ny - g * 8;
    int rb, cb;
    if (rem >= 8) {
        int r = bid - g * G;
        rb = g * 8 + (r & 7);
        cb = r >> 3;
    } else {
        int t = bid - g * G;
        rb = g * 8 + t % rem;
        cb = t / rem;
    }
    int m0 = rb * BM, n0 = cb * BN;

    int fm = lane & 15;
    int q = lane >> 4;

    int srow = lane >> 2;
    int sch = (lane & 3) * 8;
    u16* lA0 = &sA[(wave * 32) * BK];
    u16* lA1 = &sA[(wave * 32 + 16) * BK];
    u16* lB0 = &sB[(wave * 32) * BK];
    u16* lB1 = &sB[(wave * 32 + 16) * BK];
    int ar0 = min(m0 + wave * 32 + srow, M - 1);
    int ar1 = min(m0 + wave * 32 + 16 + srow, M - 1);
    int br0 = min(n0 + wave * 32 + srow, Ntot - 1);
    int br1 = min(n0 + wave * 32 + 16 + srow, Ntot - 1);

    float4v acc[4][4];
#pragma unroll
    for (int i = 0; i < 4; i++)
#pragma unroll
        for (int j = 0; j < 4; j++) acc[i][j] = (float4v){0.f, 0.f, 0.f, 0.f};

    for (int kc = 0; kc < K; kc += BK) {
        gload16(&A16[(size_t)ar0 * K + kc + sch], lA0);
        gload16(&A16[(size_t)ar1 * K + kc + sch], lA1);
        gload16(&BT[(size_t)br0 * K + kc + sch], lB0);
        gload16(&BT[(size_t)br1 * K + kc + sch], lB1);
        __syncthreads();

        half8 ah[4];
#pragma unroll
        for (int mi = 0; mi < 4; mi++)
            ah[mi] = *(const half8*)&sA[(wr * 64 + mi * 16 + fm) * BK + q * 8];
#pragma unroll
        for (int ni = 0; ni < 4; ni++) {
            half8 bh = *(const half8*)&sB[(wc * 64 + ni * 16 + fm) * BK + q * 8];
#pragma unroll
            for (int mi = 0; mi < 4; mi++)
                acc[mi][ni] = __builtin_amdgcn_mfma_f32_16x16x32_f16(ah[mi], bh, acc[mi][ni], 0, 0, 0);
        }
        __syncthreads();
    }

#pragma unroll
    for (int mi = 0; mi < 4; mi++) {
#pragma unroll
        for (int ni = 0; ni < 4; ni++) {
            int colg = n0 + wc * 64 + ni * 16 + fm;
            if (colg >= Ntot) continue;
            int cg = colg;
            if (pad121 && colg < Nb) {
                int hh = (colg * 1084) >> 17;   // colg/121 for colg<484
                cg = colg + hh;                 // head*122 + class
            }
#pragma unroll
            for (int r = 0; r < 4; r++) {
                int rowg = m0 + wr * 64 + mi * 16 + q * 4 + r;
                if (rowg >= M) continue;
                float v = acc[mi][ni][r];
                if (colg < Nb) {
                    Cb[(size_t)rowg * strideB + cg] = f2h(v);
                } else {
                    int cf = colg - Nb;
                    Cf[(size_t)rowg * strideF + cf] = v + biasf[cf];
                }
            }
        }
    }
}

// ---------------- wave-per-node attention coefficients, C=64 (layers 1/2) ----------------
__global__ __launch_bounds__(256) void alpha_wave_256(const u16* __restrict__ xh,
                                                      const float* __restrict__ a_s,
                                                      const float* __restrict__ a_d,
                                                      float* __restrict__ as_o,
                                                      float* __restrict__ ad_o, int N) {
    int lane = threadIdx.x & 63;
    int n = blockIdx.x * 4 + (threadIdx.x >> 6);
    if (n >= N) return;
    int c = lane * 4;
    uint2 v = *(const uint2*)&xh[(size_t)n * HC12 + c];
    float4 s4 = *(const float4*)&a_s[c];
    float4 d4 = *(const float4*)&a_d[c];
    float x0 = h2f((u16)(v.x & 0xffff)), x1 = h2f((u16)(v.x >> 16));
    float x2 = h2f((u16)(v.y & 0xffff)), x3 = h2f((u16)(v.y >> 16));
    float ss = x0 * s4.x + x1 * s4.y + x2 * s4.z + x3 * s4.w;
    float sd = x0 * d4.x + x1 * d4.y + x2 * d4.z + x3 * d4.w;
#pragma unroll
    for (int o = 1; o < 16; o <<= 1) {
        ss += __shfl_xor(ss, o, 64);
        sd += __shfl_xor(sd, o, 64);
    }
    if ((lane & 15) == 0) {
        as_o[n * 4 + (lane >> 4)] = ss;
        ad_o[n * 4 + (lane >> 4)] = sd;
    }
}

// ---------------- wave-per-node layer-3 attention coefficients (padded xh3) ----------------
// lane l<61 owns classes {2l, 2l+1} across all 4 heads; full-wave shfl reduce.
__global__ __launch_bounds__(256) void alpha3_wave(const u16* __restrict__ xh3,
                                                   const float* __restrict__ a_s,
                                                   const float* __restrict__ a_d,
                                                   float* __restrict__ as_o,
                                                   float* __restrict__ ad_o, int N) {
    int lane = threadIdx.x & 63;
    int n = blockIdx.x * 4 + (threadIdx.x >> 6);
    if (n >= N) return;
    int l = min(lane, 60);
    int c0 = 2 * l;
    float m0 = (lane < 61) ? 1.f : 0.f;
    float m1 = (lane < 61 && c0 + 1 < NCLS) ? 1.f : 0.f;
    int d1 = (c0 + 1 < NCLS) ? 1 : 0;
    const u16* row = xh3 + (size_t)n * HC3P;
    float ss[4], sd[4];
#pragma unroll
    for (int h = 0; h < 4; h++) {
        u32 v = *(const u32*)&row[h * 122 + c0];
        float x0 = h2f((u16)(v & 0xffff)) * m0;
        float x1 = h2f((u16)(v >> 16)) * m1;
        int i0 = h * NCLS + c0;
        ss[h] = x0 * a_s[i0] + x1 * a_s[i0 + d1];
        sd[h] = x0 * a_d[i0] + x1 * a_d[i0 + d1];
    }
#pragma unroll
    for (int o = 1; o < 64; o <<= 1) {
#pragma unroll
        for (int h = 0; h < 4; h++) {
            ss[h] += __shfl_xor(ss[h], o, 64);
            sd[h] += __shfl_xor(sd[h], o, 64);
        }
    }
    if (lane == 0) {
#pragma unroll
        for (int h = 0; h < 4; h++) {
            as_o[n * 4 + h] = ss[h];
            ad_o[n * 4 + h] = sd[h];
        }
    }
}

// ---------------- fused softmax stats + per-edge alpha ----------------
__global__ __launch_bounds__(256) void stats_alpha_kernel(const int* __restrict__ rowp,
                                                          const int* __restrict__ col,
                                                          const float* __restrict__ asrc,
                                                          const float* __restrict__ adst,
                                                          float* __restrict__ alphaE, int N) {
    int i = blockIdx.x * 256 + threadIdx.x;
    if (i >= N * 4) return;
    int n = i >> 2, h = i & 3;
    int r0 = rowp[n], r1 = rowp[n + 1];
    float ad = adst[i];
    float m = -3.4e38f, s = 0.f;
    for (int e = r0; e < r1; e++) {
        int sc = col[e];
        float l = lrelu(asrc[sc * 4 + h] + ad);
        float nm = fmaxf(m, l);
        s = s * __expf(m - nm) + __expf(l - nm);
        m = nm;
    }
    float rd = 1.f / (s + 1e-16f);
    for (int e = r0; e < r1; e++) {
        int sc = col[e];
        float l = lrelu(asrc[sc * 4 + h] + ad);
        alphaE[(size_t)e * 4 + h] = __expf(l - m) * rd;
    }
}

// ---------------- wave-per-node aggregate, HC=256 (layers 1/2) ----------------
__global__ __launch_bounds__(256) void agg_wave_256(const u16* __restrict__ xh,
                                                    const int* __restrict__ rowp,
                                                    const int* __restrict__ col,
                                                    const float* __restrict__ alphaE,
                                                    const float* __restrict__ bias,
                                                    const float* __restrict__ res,
                                                    float* __restrict__ outf,
                                                    u16* __restrict__ out16, int N) {
    int lane = threadIdx.x & 63;
    int n = blockIdx.x * 4 + (threadIdx.x >> 6);
    if (n >= N) return;
    int r0 = rowp[n], r1 = rowp[n + 1];
    int c = lane * 4;
    int h = lane >> 4;
    float a0 = 0.f, a1 = 0.f, a2 = 0.f, a3 = 0.f;
    for (int kb = r0; kb < r1; kb += 16) {
        int cn = min(16, r1 - kb);
        int cidx = col[kb + (lane & 15)];
        float alv = alphaE[(size_t)kb * 4 + lane];
#pragma unroll 4
        for (int k = 0; k < cn; k++) {
            int src = __shfl(cidx, k, 64);
            float al = __shfl(alv, k * 4 + h, 64);
            uint2 v = *(const uint2*)&xh[(size_t)src * HC12 + c];
            a0 += al * h2f((u16)(v.x & 0xffff));
            a1 += al * h2f((u16)(v.x >> 16));
            a2 += al * h2f((u16)(v.y & 0xffff));
            a3 += al * h2f((u16)(v.y >> 16));
        }
    }
    float4 bv = *(const float4*)&bias[c];
    float4 rv = *(const float4*)&res[(size_t)n * HC12 + c];
    float v0 = a0 + bv.x + rv.x;
    float v1 = a1 + bv.y + rv.y;
    float v2 = a2 + bv.z + rv.z;
    float v3 = a3 + bv.w + rv.w;
    float e0 = v0 > 0.f ? v0 : expm1f(v0);
    float e1 = v1 > 0.f ? v1 : expm1f(v1);
    float e2 = v2 > 0.f ? v2 : expm1f(v2);
    float e3 = v3 > 0.f ? v3 : expm1f(v3);
    if (outf) {
        float4 o4; o4.x = e0; o4.y = e1; o4.z = e2; o4.w = e3;
        *(float4*)&outf[(size_t)n * HC12 + c] = o4;
    }
    union { u16 u[4]; uint2 v; } p;
    p.u[0] = f2h(e0); p.u[1] = f2h(e1); p.u[2] = f2h(e2); p.u[3] = f2h(e3);
    *(uint2*)&out16[(size_t)n * HC12 + c] = p.v;
}

// ---------------- wave-per-node layer-3 aggregate (padded xh3, no LDS) ----------------
// lane l<61 owns classes {2l,2l+1} for ALL 4 heads: 8 indep acc chains, head-mean in regs.
__global__ __launch_bounds__(256) void agg_wave_out(const u16* __restrict__ xh3,
                                                    const int* __restrict__ rowp,
                                                    const int* __restrict__ col,
                                                    const float* __restrict__ alphaE,
                                                    const float* __restrict__ b3,
                                                    const float* __restrict__ lin3,
                                                    float* __restrict__ out, int N) {
    int lane = threadIdx.x & 63;
    int n = blockIdx.x * 4 + (threadIdx.x >> 6);
    if (n >= N) return;
    int r0 = rowp[n], r1 = rowp[n + 1];
    int l = min(lane, 60);
    int c0 = 2 * l;
    float acc[4][2];
#pragma unroll
    for (int h = 0; h < 4; h++) { acc[h][0] = 0.f; acc[h][1] = 0.f; }
    for (int kb = r0; kb < r1; kb += 16) {
        int cn = min(16, r1 - kb);
        int cidx = col[kb + (lane & 15)];
        float alv = alphaE[(size_t)kb * 4 + lane];
#pragma unroll 4
        for (int k = 0; k < cn; k++) {
            int src = __shfl(cidx, k, 64);
            float al0 = __shfl(alv, k * 4 + 0, 64);
            float al1 = __shfl(alv, k * 4 + 1, 64);
            float al2 = __shfl(alv, k * 4 + 2, 64);
            float al3 = __shfl(alv, k * 4 + 3, 64);
            const u16* row = xh3 + (size_t)src * HC3P + c0;
            u32 v0 = *(const u32*)&row[0];
            u32 v1 = *(const u32*)&row[122];
            u32 v2 = *(const u32*)&row[244];
            u32 v3 = *(const u32*)&row[366];
            acc[0][0] += al0 * h2f((u16)(v0 & 0xffff));
            acc[0][1] += al0 * h2f((u16)(v0 >> 16));
            acc[1][0] += al1 * h2f((u16)(v1 & 0xffff));
            acc[1][1] += al1 * h2f((u16)(v1 >> 16));
            acc[2][0] += al2 * h2f((u16)(v2 & 0xffff));
            acc[2][1] += al2 * h2f((u16)(v2 >> 16));
            acc[3][0] += al3 * h2f((u16)(v3 & 0xffff));
            acc[3][1] += al3 * h2f((u16)(v3 >> 16));
        }
    }
    if (lane < 61) {
        float o0 = 0.25f * (acc[0][0] + acc[1][0] + acc[2][0] + acc[3][0])
                   + b3[c0] + lin3[(size_t)n * NCLS + c0];
        out[(size_t)n * NCLS + c0] = o0;
        if (c0 + 1 < NCLS) {
            float o1 = 0.25f * (acc[0][1] + acc[1][1] + acc[2][1] + acc[3][1])
                       + b3[c0 + 1] + lin3[(size_t)n * NCLS + c0 + 1];
            out[(size_t)n * NCLS + c0 + 1] = o1;
        }
    }
}

extern "C" void kernel_launch(void* const* d_in, const int* in_sizes, int n_in,
                              void* d_out, int out_size, void* d_ws, size_t ws_size,
                              hipStream_t stream) {
    const float* x   = (const float*)d_in[0];
    const int*   ei  = (const int*)d_in[1];
    const float* W1  = (const float*)d_in[2];
    const float* a1s = (const float*)d_in[3];
    const float* a1d = (const float*)d_in[4];
    const float* b1  = (const float*)d_in[5];
    const float* l1W = (const float*)d_in[6];
    const float* l1b = (const float*)d_in[7];
    const float* W2  = (const float*)d_in[8];
    const float* a2s = (const float*)d_in[9];
    const float* a2d = (const float*)d_in[10];
    const float* b2  = (const float*)d_in[11];
    const float* W3  = (const float*)d_in[12];
    const float* a3s = (const float*)d_in[13];
    const float* a3d = (const float*)d_in[14];
    const float* b3  = (const float*)d_in[15];
    const float* l3W = (const float*)d_in[16];
    const float* l3b = (const float*)d_in[17];

    const int N = in_sizes[0] / F_IN;   // 50000
    const int E = in_sizes[1] / 2;      // 400000
    const int* srcv = ei;
    const int* dstv = ei + E;

    char* ws = (char*)d_ws;
    size_t off = 0;
    auto alloc = [&](size_t bytes) -> char* {
        char* p = ws + off;
        off += (bytes + 255) & ~(size_t)255;
        return p;
    };
    u16*   xh   = (u16*)alloc((size_t)N * HC3P * 2 + 256);
    u16*   x16  = (u16*)alloc((size_t)N * F_IN * 2);
    u16*   h1f  = (u16*)alloc((size_t)N * HC12 * 2);
    u16*   h2f  = (u16*)alloc((size_t)N * HC12 * 2);
    float* h1   = (float*)alloc((size_t)N * HC12 * 4);
    float* lin  = (float*)alloc((size_t)N * NCLS * 4);
    float* as_  = (float*)alloc((size_t)N * 4 * 4);
    float* ad_  = (float*)alloc((size_t)N * 4 * 4);
    int* rowp   = (int*)alloc((size_t)(N + 1) * 4);
    int* degc   = (int*)alloc((size_t)N * 4);
    int* cur    = (int*)alloc((size_t)N * 4);
    int* col    = (int*)alloc((size_t)E * 4 + 256);
    float* alphaE = (float*)alloc((size_t)E * 4 * 4 + 256);
    u16* C1 = (u16*)alloc((size_t)512 * 128 * 2);
    u16* C2 = (u16*)alloc((size_t)256 * 256 * 2);
    u16* C3 = (u16*)alloc((size_t)605 * 256 * 2);
    (void)ws_size; (void)n_in; (void)out_size;

    // ---- CSR build ----
    hipMemsetAsync(degc, 0, (size_t)N * 4, stream);
    hipMemsetAsync(cur, 0, (size_t)N * 4, stream);
    hist_kernel<<<(E + 255) / 256, 256, 0, stream>>>(dstv, degc, E);
    scan_kernel<<<1, 1024, 0, stream>>>(degc, rowp, N);
    scatter_kernel<<<(E + 255) / 256, 256, 0, stream>>>(srcv, dstv, rowp, cur, col, E);

    // ---- weight transpose + x conversion ----
    cvtT_all_kernel<<<(285952 + 255) / 256, 256, 0, stream>>>(W1, l1W, W2, W3, l3W, C1, C2, C3);
    xcvt_kernel<<<(N * F_IN / 8 + 255) / 256, 256, 0, stream>>>(x, x16, N * F_IN / 8);

    int ny = (N + BM - 1) / BM;
    int sgrid = (N * 4 + 255) / 256;
    int wgrid = (N + 3) / 4;

    // ---- layer 1: one GEMM, N=512 (cols 0-255 -> xh f16, 256-511 -> h1 fp32 + l1b) ----
    gemm_f16<<<4 * ny, 256, 0, stream>>>(x16, C1, N, F_IN, 512, 4, ny,
                                         256, xh, 256, 0, h1, l1b, 256);
    alpha_wave_256<<<wgrid, 256, 0, stream>>>(xh, a1s, a1d, as_, ad_, N);
    stats_alpha_kernel<<<sgrid, 256, 0, stream>>>(rowp, col, as_, ad_, alphaE, N);
    agg_wave_256<<<wgrid, 256, 0, stream>>>(xh, rowp, col, alphaE, b1, h1, h1, h1f, N);

    // ---- layer 2: N=256, f16-only output ----
    gemm_f16<<<2 * ny, 256, 0, stream>>>(h1f, C2, N, HC12, 256, 2, ny,
                                         256, xh, 256, 0, nullptr, nullptr, 0);
    alpha_wave_256<<<wgrid, 256, 0, stream>>>(xh, a2s, a2d, as_, ad_, N);
    stats_alpha_kernel<<<sgrid, 256, 0, stream>>>(rowp, col, as_, ad_, alphaE, N);
    agg_wave_256<<<wgrid, 256, 0, stream>>>(xh, rowp, col, alphaE, b2, h1, nullptr, h2f, N);

    // ---- layer 3: one GEMM, N=605, padded xh3 (stride 488), cols 484-604 -> lin fp32 + l3b ----
    gemm_f16<<<5 * ny, 256, 0, stream>>>(h2f, C3, N, HC12, 605, 5, ny,
                                         484, xh, HC3P, 1, lin, l3b, NCLS);
    alpha3_wave<<<wgrid, 256, 0, stream>>>(xh, a3s, a3d, as_, ad_, N);
    stats_alpha_kernel<<<sgrid, 256, 0, stream>>>(rowp, col, as_, ad_, alphaE, N);
    agg_wave_out<<<wgrid, 256, 0, stream>>>(xh, rowp, col, alphaE, b3, lin, (float*)d_out, N);
}